// Round 3
// baseline (115448.657 us; speedup 1.0000x reference)
//
#include <hip/hip_runtime.h>

// GRU encoder-decoder, round 3: transposed mapping, spill-free.
// 256 blocks x 1024 threads (16 waves = 4 waves/SIMD). Block owns 32 batches
// (bl = tid&31). Group g = tid>>5 (0..31) owns hidden units j0=2g, j0+1, i.e.
// 6 gate rows {q*64+2g+c}. Weight reads: natural row-major, uniform per
// half-wave (HW broadcast), immediate offsets -> L1/L2 resident.
// h state in LDS as float4 quads [kq][b] (conflict-free ds_read_b128),
// double-buffered (flip per step) -> no RAW race, 2 barriers/step.
// Key fix vs round 2: h is STREAMED through a 4-float register window inside
// the matvec (never a h[64] array) -> no scratch spill (round 2: 67 GB spill).

#define NB 32

__device__ __forceinline__ float sgm(float v) { return 1.f / (1.f + __expf(-v)); }
__device__ __forceinline__ float th(float v)  { float e = __expf(2.f * v); return 1.f - 2.f / (e + 1.f); }

struct P {
  const float *x;
  const float *eWi0, *eWh0, *ebi0, *ebh0, *eWi1, *eWh1, *ebi1, *ebh1;
  const float *dWi0, *dWh0, *dbi0, *dbh0, *dWi1, *dWh1, *dbi1, *dbh1;
  const float *oW, *ob;
  float *out;
};

// acc[6] += rows {j0, j0+1, 64+j0, 64+j0+1, 128+j0, 128+j0+1} of W (192x64
// row-major) dotted with h (LDS float4 quads [kq][bl]). h streamed 16B at a
// time; weights 16B at immediate offsets (uniform per half-wave -> broadcast).
__device__ __forceinline__ void mv6(const float* __restrict__ W, int j0,
                                    const float4* __restrict__ h4, int bl,
                                    float acc[6]) {
  const float4* r0 = (const float4*)(W + (size_t)j0 * 64);
  const float4* r1 = (const float4*)(W + (size_t)(j0 + 1) * 64);
  const float4* r2 = (const float4*)(W + (size_t)(64 + j0) * 64);
  const float4* r3 = (const float4*)(W + (size_t)(64 + j0 + 1) * 64);
  const float4* r4 = (const float4*)(W + (size_t)(128 + j0) * 64);
  const float4* r5 = (const float4*)(W + (size_t)(128 + j0 + 1) * 64);
#pragma unroll
  for (int kq = 0; kq < 16; ++kq) {
    float4 hv = h4[kq * NB + bl];        // ds_read_b128, conflict-free
    float4 w0 = r0[kq], w1 = r1[kq], w2 = r2[kq];
    float4 w3 = r3[kq], w4 = r4[kq], w5 = r5[kq];
    acc[0] += w0.x * hv.x + w0.y * hv.y + w0.z * hv.z + w0.w * hv.w;
    acc[1] += w1.x * hv.x + w1.y * hv.y + w1.z * hv.z + w1.w * hv.w;
    acc[2] += w2.x * hv.x + w2.y * hv.y + w2.z * hv.z + w2.w * hv.w;
    acc[3] += w3.x * hv.x + w3.y * hv.y + w3.z * hv.z + w3.w * hv.w;
    acc[4] += w4.x * hv.x + w4.y * hv.y + w4.z * hv.z + w4.w * hv.w;
    acc[5] += w5.x * hv.x + w5.y * hv.y + w5.z * hv.z + w5.w * hv.w;
  }
}

// read/write this thread's own pair h[j0], h[j0+1] for batch bl (8B, aligned)
__device__ __forceinline__ float2 own_rd(const float4* h4, int g, int bl) {
  return ((const float2*)h4)[(((g >> 1) * NB) + bl) * 2 + (g & 1)];
}
__device__ __forceinline__ void own_wr(float4* h4, int g, int bl, float2 v) {
  ((float2*)h4)[(((g >> 1) * NB) + bl) * 2 + (g & 1)] = v;
}

__global__ __launch_bounds__(1024, 4) void gru_main(P p) {
  __shared__ float4 h0A[16 * NB], h0B[16 * NB], h1A[16 * NB], h1B[16 * NB];
  __shared__ float ps[16 * NB];

  const int tid = threadIdx.x;
  const int bl = tid & 31;          // batch lane
  const int g = tid >> 5;           // group 0..31, owns j0=2g, 2g+1
  const int w = tid >> 6;           // wave 0..15
  const int b = blockIdx.x * NB + bl;
  const int j0 = 2 * g;

  if (tid < 16 * NB) {
    h0A[tid] = make_float4(0.f, 0.f, 0.f, 0.f);
    h1A[tid] = make_float4(0.f, 0.f, 0.f, 0.f);
  }
  __syncthreads();

  float4 *h0c = h0A, *h0n = h0B, *h1c = h1A, *h1n = h1B;
  const float ob = p.ob[0];

  // ================= encoder: 512 steps =================
  {
    // per-thread constants: input weights (rows of 192x2) + folded biases
    float2 wxr0 = *(const float2*)(p.eWi0 + j0 * 2);
    float2 wxr1 = *(const float2*)(p.eWi0 + (j0 + 1) * 2);
    float2 wxz0 = *(const float2*)(p.eWi0 + (64 + j0) * 2);
    float2 wxz1 = *(const float2*)(p.eWi0 + (64 + j0 + 1) * 2);
    float2 wxn0 = *(const float2*)(p.eWi0 + (128 + j0) * 2);
    float2 wxn1 = *(const float2*)(p.eWi0 + (128 + j0 + 1) * 2);
    float bR0[2], bZ0[2], biN0[2], bhN0[2];  // cell0
    float bR1[2], bZ1[2], biN1[2], bhN1[2];  // cell1
#pragma unroll
    for (int c = 0; c < 2; ++c) {
      bR0[c] = p.ebi0[j0 + c] + p.ebh0[j0 + c];
      bZ0[c] = p.ebi0[64 + j0 + c] + p.ebh0[64 + j0 + c];
      biN0[c] = p.ebi0[128 + j0 + c]; bhN0[c] = p.ebh0[128 + j0 + c];
      bR1[c] = p.ebi1[j0 + c] + p.ebh1[j0 + c];
      bZ1[c] = p.ebi1[64 + j0 + c] + p.ebh1[64 + j0 + c];
      biN1[c] = p.ebi1[128 + j0 + c]; bhN1[c] = p.ebh1[128 + j0 + c];
    }

    for (int t = 0; t < 512; ++t) {
      // ---- cell0 ----
      float acc[6] = {0.f, 0.f, 0.f, 0.f, 0.f, 0.f};
      mv6(p.eWh0, j0, h0c, bl, acc);
      float2 xt = *(const float2*)(p.x + ((size_t)b * 512 + t) * 2);
      float2 o0 = own_rd(h0c, g, bl);
      {
        float r0 = sgm(acc[0] + wxr0.x * xt.x + wxr0.y * xt.y + bR0[0]);
        float r1 = sgm(acc[1] + wxr1.x * xt.x + wxr1.y * xt.y + bR0[1]);
        float z0 = sgm(acc[2] + wxz0.x * xt.x + wxz0.y * xt.y + bZ0[0]);
        float z1 = sgm(acc[3] + wxz1.x * xt.x + wxz1.y * xt.y + bZ0[1]);
        float n0 = th(wxn0.x * xt.x + wxn0.y * xt.y + biN0[0] + r0 * (acc[4] + bhN0[0]));
        float n1 = th(wxn1.x * xt.x + wxn1.y * xt.y + biN0[1] + r1 * (acc[5] + bhN0[1]));
        own_wr(h0n, g, bl, make_float2((1.f - z0) * n0 + z0 * o0.x,
                                       (1.f - z1) * n1 + z1 * o0.y));
      }
      __syncthreads();

      // ---- cell1 ----
      float ai[6] = {0.f, 0.f, 0.f, 0.f, 0.f, 0.f};
      mv6(p.eWi1, j0, h0n, bl, ai);
      float ah[6] = {0.f, 0.f, 0.f, 0.f, 0.f, 0.f};
      mv6(p.eWh1, j0, h1c, bl, ah);
      float2 o1 = own_rd(h1c, g, bl);
      {
        float r0 = sgm(ai[0] + ah[0] + bR1[0]);
        float r1 = sgm(ai[1] + ah[1] + bR1[1]);
        float z0 = sgm(ai[2] + ah[2] + bZ1[0]);
        float z1 = sgm(ai[3] + ah[3] + bZ1[1]);
        float n0 = th(ai[4] + biN1[0] + r0 * (ah[4] + bhN1[0]));
        float n1 = th(ai[5] + biN1[1] + r1 * (ah[5] + bhN1[1]));
        own_wr(h1n, g, bl, make_float2((1.f - z0) * n0 + z0 * o1.x,
                                       (1.f - z1) * n1 + z1 * o1.y));
      }
      __syncthreads();
      float4* tmp;
      tmp = h0c; h0c = h0n; h0n = tmp;
      tmp = h1c; h1c = h1n; h1n = tmp;
    }
  }

  // ================= decoder: 180 steps =================
  {
    float wd[6];
    float bR0[2], bZ0[2], biN0[2], bhN0[2];
    float bR1[2], bZ1[2], biN1[2], bhN1[2];
#pragma unroll
    for (int c = 0; c < 2; ++c) {
      wd[c] = p.dWi0[j0 + c];
      wd[2 + c] = p.dWi0[64 + j0 + c];
      wd[4 + c] = p.dWi0[128 + j0 + c];
      bR0[c] = p.dbi0[j0 + c] + p.dbh0[j0 + c];
      bZ0[c] = p.dbi0[64 + j0 + c] + p.dbh0[64 + j0 + c];
      biN0[c] = p.dbi0[128 + j0 + c]; bhN0[c] = p.dbh0[128 + j0 + c];
      bR1[c] = p.dbi1[j0 + c] + p.dbh1[j0 + c];
      bZ1[c] = p.dbi1[64 + j0 + c] + p.dbh1[64 + j0 + c];
      biN1[c] = p.dbi1[128 + j0 + c]; bhN1[c] = p.dbh1[128 + j0 + c];
    }
    const float oW0 = p.oW[j0], oW1 = p.oW[j0 + 1];

    float prev = 0.f;
    for (int t = 0; t < 180; ++t) {
      // ---- cell0 (input = prev scalar) ----
      float acc[6] = {0.f, 0.f, 0.f, 0.f, 0.f, 0.f};
      mv6(p.dWh0, j0, h0c, bl, acc);
      float2 o0 = own_rd(h0c, g, bl);
      {
        float r0 = sgm(acc[0] + wd[0] * prev + bR0[0]);
        float r1 = sgm(acc[1] + wd[1] * prev + bR0[1]);
        float z0 = sgm(acc[2] + wd[2] * prev + bZ0[0]);
        float z1 = sgm(acc[3] + wd[3] * prev + bZ0[1]);
        float n0 = th(wd[4] * prev + biN0[0] + r0 * (acc[4] + bhN0[0]));
        float n1 = th(wd[5] * prev + biN0[1] + r1 * (acc[5] + bhN0[1]));
        own_wr(h0n, g, bl, make_float2((1.f - z0) * n0 + z0 * o0.x,
                                       (1.f - z1) * n1 + z1 * o0.y));
      }
      __syncthreads();

      // ---- cell1 ----
      float ai[6] = {0.f, 0.f, 0.f, 0.f, 0.f, 0.f};
      mv6(p.dWi1, j0, h0n, bl, ai);
      float ah[6] = {0.f, 0.f, 0.f, 0.f, 0.f, 0.f};
      mv6(p.dWh1, j0, h1c, bl, ah);
      float2 o1 = own_rd(h1c, g, bl);
      float hn0, hn1;
      {
        float r0 = sgm(ai[0] + ah[0] + bR1[0]);
        float r1 = sgm(ai[1] + ah[1] + bR1[1]);
        float z0 = sgm(ai[2] + ah[2] + bZ1[0]);
        float z1 = sgm(ai[3] + ah[3] + bZ1[1]);
        float n0 = th(ai[4] + biN1[0] + r0 * (ah[4] + bhN1[0]));
        float n1 = th(ai[5] + biN1[1] + r1 * (ah[5] + bhN1[1]));
        hn0 = (1.f - z0) * n0 + z0 * o1.x;
        hn1 = (1.f - z1) * n1 + z1 * o1.y;
        own_wr(h1n, g, bl, make_float2(hn0, hn1));
      }
      // ---- output dot: out[b] = sum_j oW[j]*h1new[j][b] + ob ----
      float pv = oW0 * hn0 + oW1 * hn1;
      pv += __shfl_xor(pv, 32, 64);          // combine the wave's two groups
      if ((tid & 32) == 0) ps[w * NB + bl] = pv;
      __syncthreads();                        // ps ready AND h1n drained
      float sum = ob;
#pragma unroll
      for (int q = 0; q < 16; ++q) sum += ps[q * NB + bl];
      prev = sum;
      if (g == 0) p.out[(size_t)b * 180 + t] = sum;
      float4* tmp;
      tmp = h0c; h0c = h0n; h0n = tmp;
      tmp = h1c; h1c = h1n; h1n = tmp;
    }
  }
}

extern "C" void kernel_launch(void* const* d_in, const int* in_sizes, int n_in,
                              void* d_out, int out_size, void* d_ws, size_t ws_size,
                              hipStream_t stream) {
  P p;
  p.x    = (const float*)d_in[0];
  p.eWi0 = (const float*)d_in[1];
  p.eWh0 = (const float*)d_in[2];
  p.ebi0 = (const float*)d_in[3];
  p.ebh0 = (const float*)d_in[4];
  p.eWi1 = (const float*)d_in[5];
  p.eWh1 = (const float*)d_in[6];
  p.ebi1 = (const float*)d_in[7];
  p.ebh1 = (const float*)d_in[8];
  p.dWi0 = (const float*)d_in[9];
  p.dWh0 = (const float*)d_in[10];
  p.dbi0 = (const float*)d_in[11];
  p.dbh0 = (const float*)d_in[12];
  p.dWi1 = (const float*)d_in[13];
  p.dWh1 = (const float*)d_in[14];
  p.dbi1 = (const float*)d_in[15];
  p.dbh1 = (const float*)d_in[16];
  p.oW   = (const float*)d_in[17];
  p.ob   = (const float*)d_in[18];
  p.out  = (float*)d_out;

  gru_main<<<dim3(256), dim3(1024), 0, stream>>>(p);
}